// Round 12
// baseline (443.238 us; speedup 1.0000x reference)
//
#include <hip/hip_runtime.h>
#include <cstdint>
#include <cstddef>

typedef unsigned short u16;
typedef __attribute__((ext_vector_type(8))) short bf16x8;
typedef __attribute__((ext_vector_type(4))) float f32x4;

__device__ __forceinline__ float bf2f(u16 u) {
  unsigned v = ((unsigned)u) << 16;
  return __builtin_bit_cast(float, v);
}
__device__ __forceinline__ u16 f2bf(float f) {
  unsigned u = __builtin_bit_cast(unsigned, f);
  u = (u + 0x7FFFu + ((u >> 16) & 1u)) >> 16;
  return (u16)u;
}

// async global->LDS, 16B per lane. LDS dest semantics: wave-uniform base + lane*16.
__device__ __forceinline__ void gload16(const void* g, void* l) {
  __builtin_amdgcn_global_load_lds(
      (const __attribute__((address_space(1))) void*)g,
      (__attribute__((address_space(3))) void*)l,
      16, 0, 0);
}

// Guideline-4 XOR swizzle for 128B-row tiles: 16B-slot bits (6:4) ^= row bits
// (9:7). Involution; verified 0 bank conflicts (round 4).
__device__ __forceinline__ int swz(int lb) { return lb ^ (((lb >> 7) & 7) << 4); }

// ---------------- elementwise f32 -> bf16 ----------------
__global__ __launch_bounds__(256) void f32_to_bf16_kernel(
    const float* __restrict__ in, u16* __restrict__ out, int n) {
  int i = (blockIdx.x * 256 + threadIdx.x) * 4;
  if (i < n) {
    float4 v = *(const float4*)(in + i);
    ushort4 o;
    o.x = f2bf(v.x); o.y = f2bf(v.y); o.z = f2bf(v.z); o.w = f2bf(v.w);
    *(ushort4*)(out + i) = o;
  }
}

// ---------------- transpose f32[R][C] -> bf16[C][R] ----------------
__global__ void transpose_f32_bf16T_kernel(
    const float* __restrict__ in, u16* __restrict__ out, int R, int C) {
  __shared__ float tile[32][33];
  const int bx = blockIdx.x * 32;  // C coord
  const int by = blockIdx.y * 32;  // R coord
  const int tx = threadIdx.x, ty = threadIdx.y;  // (32,8)
#pragma unroll
  for (int i = 0; i < 32; i += 8)
    tile[ty + i][tx] = in[(size_t)(by + ty + i) * C + bx + tx];
  __syncthreads();
#pragma unroll
  for (int i = 0; i < 32; i += 8)
    out[(size_t)(bx + ty + i) * R + by + tx] = f2bf(tile[tx][ty + i]);
}

// === 256-wide MFMA GEMM: A via LDS (in-place staged), B DIRECT to registers ===
// C[M][N] = A[M][K] * Bt[N][K]^T. BM=256, BK=64, BN in {256,128}. 8 waves.
// LDS-bandwidth theory (r4-r10 invariances): per-CU LDS throughput is the
// shared wall. Remove B from LDS: ds_reads 24->16/wave/tile, LDS writes
// 96KB->32KB/tile. B frags load global->VGPR (compiler-tracked waits),
// double-buffered one K-tile ahead (ping-pong bhX/bhY, flight >= 2 phases).
// Column-major XCD walk keeps each XCD's B slice L2-resident.
// A staging: 32KB single buffer, in-place: Alo overwritten p2 (read p1),
// Ahi p4 (read p3). Counted drains: p2-end vmcnt(BL+2), p4-end vmcnt(2BL+2).
// *** launch_bounds(512, 1): hipcc treats arg2 as min BLOCKS/CU (r5/r11
// lesson) -> VGPR cap 256. Reg-B needs ~240; (512,2) capped at 128 and
// spilled catastrophically in r11 (WRITE_SIZE 100MB scratch). ***
// EPI 0: split xz -> xp bf16 / silu(z) bf16, ld 2048.  EPI 3: f32 store, ld N.
template <int BN, int EPI>
__global__ __launch_bounds__(512, 1) void gemm256(
    const u16* __restrict__ Ap, const u16* __restrict__ Btp,
    int M, int N, int K, int gy,
    void* __restrict__ o0, void* __restrict__ o1) {
  constexpr int NFR = BN / 64;   // n-frags per wave (4 or 2)
  constexpr int NFH = NFR / 2;   // n-frags per quadrant (2 or 1)
  constexpr int BL = 2 * NFH;    // B reg-loads per half per wave (4 or 2)
  constexpr int WN = BN / 4;     // wave's N extent
  __shared__ __align__(1024) char smem[32768];  // A only, single buffer

  const int tid = threadIdx.x;
  const int wid = tid >> 6, lane = tid & 63;
  const int wr = wid >> 2, wc = wid & 3;
  const int l16 = lane & 15, lk = lane >> 4;

  // bijective XCD swizzle (gridDim.x % 8 == 0) + COLUMN-major walk within the
  // XCD chunk: B col-tiles per XCD = 1-2 -> L2-resident (essential for reg-B).
  const int nwg = gridDim.x, bid = blockIdx.x;
  const int rb = (bid & 7) * (nwg >> 3) + (bid >> 3);
  const int by = rb % gy, bx = rb / gy;
  const int m0 = by * 256, n0 = bx * BN;

  // A staging sources (inverse-swizzled per-lane global addr, rule #21).
  // A unit i (8KB) = rows [64i,64i+64); A-lo = units {0,2}, A-hi = {1,3}.
  unsigned aoff[4];
#pragma unroll
  for (int i = 0; i < 4; ++i) {
    int lb = swz(i * 8192 + tid * 16);
    aoff[i] = (unsigned)(m0 + (lb >> 7)) * K + ((lb & 127) >> 1);
  }
  auto stageA = [&](int kt, int h) {
    char* dst = smem + (wid << 10);
    gload16(Ap + aoff[h] + kt * 64, dst + h * 8192);
    gload16(Ap + aoff[h + 2] + kt * 64, dst + (h + 2) * 8192);
  };
  auto offA = [&](int f, int kk) {
    return swz((wr * 128 + f * 16 + l16) * 128 + kk * 64 + lk * 16);
  };

  // B fragment base element-offsets (per-lane; 4 lk-lanes = 64B coalesced)
  unsigned boff[2][NFH];
#pragma unroll
  for (int h = 0; h < 2; ++h)
#pragma unroll
    for (int nf = 0; nf < NFH; ++nf)
      boff[h][nf] =
          (unsigned)(n0 + wc * WN + (h * NFH + nf) * 16 + l16) * K + lk * 8;

  f32x4 acc[8][NFR];
#pragma unroll
  for (int f = 0; f < 8; ++f)
#pragma unroll
    for (int n = 0; n < NFR; ++n) {
      f32x4 z = {0.f, 0.f, 0.f, 0.f};
      acc[f][n] = z;
    }

  bf16x8 bhX[2][NFH][2], bhY[2][NFH][2];
  auto loadB = [&](bf16x8 (&dst)[2][NFH][2], int h, int kt) {
#pragma unroll
    for (int nf = 0; nf < NFH; ++nf)
#pragma unroll
      for (int kk = 0; kk < 2; ++kk)
        dst[h][nf][kk] =
            *(const bf16x8*)(Btp + boff[h][nf] + kt * 64 + kk * 32);
  };

  const int NT = K >> 6;  // K-tiles (even, >= 4 for all our launches)

  // prologue: tile0 A (all 4 units) + tile0 B regs; full drain once.
  stageA(0, 0); stageA(0, 1);
  loadB(bhX, 0, 0); loadB(bhX, 1, 0);
  asm volatile("s_waitcnt vmcnt(0)" ::: "memory");
  __builtin_amdgcn_s_barrier();

  auto body = [&](int kt, bf16x8 (&cur)[2][NFH][2],
                  bf16x8 (&nxt)[2][NFH][2], bool hasnext) {
    bf16x8 af[4][2];
    // ---- p1: ds_read A-lo(t); MFMA lo x lo (cur[0])
#pragma unroll
    for (int j = 0; j < 4; ++j)
#pragma unroll
      for (int kk = 0; kk < 2; ++kk)
        af[j][kk] = *(const bf16x8*)(smem + offA(j, kk));
    __builtin_amdgcn_s_barrier();
    asm volatile("s_waitcnt lgkmcnt(0)" ::: "memory");
    __builtin_amdgcn_sched_barrier(0);
    __builtin_amdgcn_s_setprio(1);
#pragma unroll
    for (int j = 0; j < 4; ++j)
#pragma unroll
      for (int n2 = 0; n2 < NFH; ++n2)
#pragma unroll
        for (int kk = 0; kk < 2; ++kk)
          acc[j][n2] = __builtin_amdgcn_mfma_f32_16x16x32_bf16(
              af[j][kk], cur[0][n2][kk], acc[j][n2], 0, 0, 0);
    __builtin_amdgcn_s_setprio(0);
    __builtin_amdgcn_s_barrier();  // all waves done reading A-lo(t)

    // ---- p2: stage A-lo(t+1) in place; MFMA lo x hi (cur[1]); drain A-hi(t)
    if (hasnext) stageA(kt + 1, 0);
    __builtin_amdgcn_s_setprio(1);
#pragma unroll
    for (int j = 0; j < 4; ++j)
#pragma unroll
      for (int n2 = 0; n2 < NFH; ++n2)
#pragma unroll
        for (int kk = 0; kk < 2; ++kk)
          acc[j][NFH + n2] = __builtin_amdgcn_mfma_f32_16x16x32_bf16(
              af[j][kk], cur[1][n2][kk], acc[j][NFH + n2], 0, 0, 0);
    __builtin_amdgcn_s_setprio(0);
    if (hasnext) {
      if constexpr (BL == 4) asm volatile("s_waitcnt vmcnt(6)" ::: "memory");
      else                   asm volatile("s_waitcnt vmcnt(4)" ::: "memory");
    } else {
      asm volatile("s_waitcnt vmcnt(0)" ::: "memory");
    }
    __builtin_amdgcn_s_barrier();

    // ---- p3: ds_read A-hi(t); issue nxt-lo(t+1) B regs; MFMA hi x hi
#pragma unroll
    for (int j = 0; j < 4; ++j)
#pragma unroll
      for (int kk = 0; kk < 2; ++kk)
        af[j][kk] = *(const bf16x8*)(smem + offA(4 + j, kk));
    if (hasnext) loadB(nxt, 0, kt + 1);
    __builtin_amdgcn_s_barrier();
    asm volatile("s_waitcnt lgkmcnt(0)" ::: "memory");
    __builtin_amdgcn_sched_barrier(0);
    __builtin_amdgcn_s_setprio(1);
#pragma unroll
    for (int j = 0; j < 4; ++j)
#pragma unroll
      for (int n2 = 0; n2 < NFH; ++n2)
#pragma unroll
        for (int kk = 0; kk < 2; ++kk)
          acc[4 + j][NFH + n2] = __builtin_amdgcn_mfma_f32_16x16x32_bf16(
              af[j][kk], cur[1][n2][kk], acc[4 + j][NFH + n2], 0, 0, 0);
    __builtin_amdgcn_s_setprio(0);
    __builtin_amdgcn_s_barrier();  // all waves done reading A-hi(t)

    // ---- p4: stage A-hi(t+1); issue nxt-hi(t+1); MFMA hi x lo (cur[0]);
    //      drain A-lo(t+1) (counted, never 0 mid-loop)
    if (hasnext) { stageA(kt + 1, 1); loadB(nxt, 1, kt + 1); }
    __builtin_amdgcn_s_setprio(1);
#pragma unroll
    for (int j = 0; j < 4; ++j)
#pragma unroll
      for (int n2 = 0; n2 < NFH; ++n2)
#pragma unroll
        for (int kk = 0; kk < 2; ++kk)
          acc[4 + j][n2] = __builtin_amdgcn_mfma_f32_16x16x32_bf16(
              af[j][kk], cur[0][n2][kk], acc[4 + j][n2], 0, 0, 0);
    __builtin_amdgcn_s_setprio(0);
    if (hasnext) {
      if constexpr (BL == 4) asm volatile("s_waitcnt vmcnt(10)" ::: "memory");
      else                   asm volatile("s_waitcnt vmcnt(6)" ::: "memory");
    }
    __builtin_amdgcn_s_barrier();
  };

  for (int kt = 0; kt < NT; kt += 2) {
    body(kt, bhX, bhY, true);
    body(kt + 1, bhY, bhX, kt + 2 < NT);
  }

#pragma unroll
  for (int f = 0; f < 8; ++f) {
#pragma unroll
    for (int n = 0; n < NFR; ++n) {
#pragma unroll
      for (int rr = 0; rr < 4; ++rr) {
        const int row = m0 + wr * 128 + f * 16 + lk * 4 + rr;
        const int col = n0 + wc * WN + n * 16 + l16;
        float v = acc[f][n][rr];
        if constexpr (EPI == 0) {
          if (col < 2048) {
            ((u16*)o0)[(size_t)row * 2048 + col] = f2bf(v);
          } else {
            float sv = v / (1.f + __expf(-v));  // silu
            ((u16*)o1)[(size_t)row * 2048 + (col - 2048)] = f2bf(sv);
          }
        } else {
          ((float*)o0)[(size_t)row * (size_t)N + col] = v;
        }
      }
    }
  }
}

// ---------------- small MFMA GEMM (128-tile) for skinny stages ----------------
// K range = [blockIdx.z*KS, blockIdx.z*KS + KS).
// EPI 2: v += bias[col]; softplus; clip(1e-3,0.1); bf16 (ld 2048)
// EPI 4: f32 partial store to o0 + blockIdx.z*M*96 (ld 96, split-K)
template <int BN, int NR, int EPI>
__global__ __launch_bounds__(256) void gemm_bt(
    const u16* __restrict__ A, const u16* __restrict__ Bt,
    int M, int N, int K, int KS,
    void* __restrict__ o0, const float* __restrict__ bias) {
  constexpr int BM = 128, BK = 32, MR = 4;
  __shared__ __align__(16) u16 As[BM * BK];
  __shared__ __align__(16) u16 Bs[BN * BK];
  const int tid = threadIdx.x;
  const int wid = tid >> 6, lane = tid & 63;
  const int wr = wid >> 1, wc = wid & 1;
  const int m0 = blockIdx.y * BM, n0 = blockIdx.x * BN;
  const int l16 = lane & 15, lk = lane >> 4;

  f32x4 acc[MR][NR];
#pragma unroll
  for (int m = 0; m < MR; ++m)
#pragma unroll
    for (int n = 0; n < NR; ++n) {
      f32x4 z = {0.f, 0.f, 0.f, 0.f};
      acc[m][n] = z;
    }

  constexpr int CH_A = (BM * BK * 2) / 1024;
  constexpr int CH_B = (BN * BK * 2) / 1024;

  const int kbeg = blockIdx.z * KS, kend = kbeg + KS;
  for (int k0 = kbeg; k0 < kend; k0 += BK) {
    for (int c = wid; c < CH_A; c += 4) {
      int off = c * 1024 + lane * 16;
      int e = off >> 1;
      int m = e >> 5, kk = e & 31;
      gload16(A + (size_t)(m0 + m) * K + (k0 + kk), (char*)As + off);
    }
    for (int c = wid; c < CH_B; c += 4) {
      int off = c * 1024 + lane * 16;
      int e = off >> 1;
      int n = e >> 5, kk = e & 31;
      gload16(Bt + (size_t)(n0 + n) * K + (k0 + kk), (char*)Bs + off);
    }
    __syncthreads();
    bf16x8 af[MR], bfr[NR];
#pragma unroll
    for (int m = 0; m < MR; ++m)
      af[m] = *(const bf16x8*)(As + (wr * 64 + m * 16 + l16) * BK + lk * 8);
#pragma unroll
    for (int n = 0; n < NR; ++n)
      bfr[n] = *(const bf16x8*)(Bs + (wc * (NR * 16) + n * 16 + l16) * BK + lk * 8);
#pragma unroll
    for (int m = 0; m < MR; ++m)
#pragma unroll
      for (int n = 0; n < NR; ++n)
        acc[m][n] = __builtin_amdgcn_mfma_f32_16x16x32_bf16(af[m], bfr[n], acc[m][n], 0, 0, 0);
    __syncthreads();
  }

#pragma unroll
  for (int m = 0; m < MR; ++m) {
#pragma unroll
    for (int n = 0; n < NR; ++n) {
#pragma unroll
      for (int r = 0; r < 4; ++r) {
        const int row = m0 + wr * 64 + m * 16 + (lane >> 4) * 4 + r;
        const int col = n0 + wc * (NR * 16) + n * 16 + (lane & 15);
        float v = acc[m][n][r];
        if constexpr (EPI == 2) {
          v += bias[col];
          float sp = (v > 20.f) ? v : log1pf(__expf(v));
          sp = fminf(fmaxf(sp, 1e-3f), 0.1f);
          ((u16*)o0)[(size_t)row * 2048 + col] = f2bf(sp);
        } else {
          ((float*)o0)[((size_t)blockIdx.z * M + row) * 96 + col] = v;
        }
      }
    }
  }
}

// ---------------- split-K reduce + dlt/B/C split ----------------
__global__ __launch_bounds__(256) void reduce_xdbl(
    const float* __restrict__ part, u16* __restrict__ dlt,
    float* __restrict__ Bc, float* __restrict__ Cc) {
  int idx = blockIdx.x * 256 + threadIdx.x;  // 8192*24 float4-groups
  int row = idx / 24, c4 = idx % 24;
  const float* p = part + (size_t)row * 96 + c4 * 4;
  f32x4 v = *(const f32x4*)p;
#pragma unroll
  for (int z = 1; z < 4; ++z)
    v += *(const f32x4*)(p + (size_t)z * 8192 * 96);
  int col = c4 * 4;
  if (col < 64) {
    ushort4 o;
    o.x = f2bf(v[0]); o.y = f2bf(v[1]); o.z = f2bf(v[2]); o.w = f2bf(v[3]);
    *(ushort4*)(dlt + (size_t)row * 64 + col) = o;
  } else if (col < 80) {
    *(f32x4*)(Bc + (size_t)row * 16 + (col - 64)) = v;
  } else {
    *(f32x4*)(Cc + (size_t)row * 16 + (col - 80)) = v;
  }
}

// ---------------- chunked parallel selective scan ----------------
template <int TC>
__global__ __launch_bounds__(256) void scan_pass1(
    const u16* __restrict__ xp, const u16* __restrict__ dt,
    const float* __restrict__ Bc, const float* __restrict__ A_log,
    float* __restrict__ P, float* __restrict__ Q, int NC) {
  const int di = blockIdx.x * 256 + threadIdx.x;
  const int c = blockIdx.y, b = blockIdx.z;
  __shared__ __align__(16) float Bs[TC * 16];
  {
    const float* src = Bc + (size_t)(b * 4096 + c * TC) * 16;
    for (int i = threadIdx.x; i < TC * 4; i += 256)
      *(float4*)(Bs + i * 4) = *(const float4*)(src + i * 4);
  }
  float A[16], h[16], Pp[16];
#pragma unroll
  for (int s = 0; s < 16; ++s) {
    A[s] = -__expf(A_log[di * 16 + s]);
    h[s] = 0.f;
    Pp[s] = 1.f;
  }
  __syncthreads();
  size_t gidx = (size_t)(b * 4096 + c * TC) * 2048 + di;
  for (int t = 0; t < TC; ++t, gidx += 2048) {
    float xv = bf2f(xp[gidx]), dv = bf2f(dt[gidx]);
    float dvx = dv * xv;
#pragma unroll
    for (int q = 0; q < 4; ++q) {
      f32x4 bv = ((const f32x4*)(Bs + t * 16))[q];
#pragma unroll
      for (int j = 0; j < 4; ++j) {
        int s = q * 4 + j;
        float abar = fmaf(A[s], dv, 1.f);
        h[s] = fmaf(abar, h[s], bv[j] * dvx);
        Pp[s] *= abar;
      }
    }
  }
  const size_t obase = ((size_t)(b * NC + c) * 16) * 2048 + di;
#pragma unroll
  for (int s = 0; s < 16; ++s) {
    P[obase + (size_t)s * 2048] = Pp[s];
    Q[obase + (size_t)s * 2048] = h[s];
  }
}

__global__ __launch_bounds__(256) void scan_pass2(
    const float* __restrict__ P, const float* __restrict__ Q,
    float* __restrict__ Hin, int NC) {
  const int di = blockIdx.x * 256 + threadIdx.x;
  const int s = blockIdx.y, b = blockIdx.z;
  float hin = 0.f;
  const size_t idx0 = ((size_t)(b * NC) * 16 + s) * 2048 + di;
#pragma unroll 8
  for (int c = 0; c < NC; ++c) {
    size_t idx = idx0 + (size_t)c * (16 * 2048);
    Hin[idx] = hin;
    hin = fmaf(P[idx], hin, Q[idx]);
  }
}

template <int TC>
__global__ __launch_bounds__(256) void scan_pass3(
    const u16* __restrict__ xp, const u16* __restrict__ dt,
    const u16* __restrict__ zs, const float* __restrict__ Bc,
    const float* __restrict__ Cc, const float* __restrict__ A_log,
    const float* __restrict__ Dv, const float* __restrict__ Hin,
    u16* __restrict__ Y, int NC) {
  const int di = blockIdx.x * 256 + threadIdx.x;
  const int c = blockIdx.y, b = blockIdx.z;
  __shared__ __align__(16) float Bs[TC * 16], Cs[TC * 16];
  {
    const float* srcB = Bc + (size_t)(b * 4096 + c * TC) * 16;
    const float* srcC = Cc + (size_t)(b * 4096 + c * TC) * 16;
    for (int i = threadIdx.x; i < TC * 4; i += 256) {
      *(float4*)(Bs + i * 4) = *(const float4*)(srcB + i * 4);
      *(float4*)(Cs + i * 4) = *(const float4*)(srcC + i * 4);
    }
  }
  float A[16], h[16];
  const size_t hbase = ((size_t)(b * NC + c) * 16) * 2048 + di;
#pragma unroll
  for (int s = 0; s < 16; ++s) {
    A[s] = -__expf(A_log[di * 16 + s]);
    h[s] = Hin[hbase + (size_t)s * 2048];
  }
  const float Dg = Dv[di];
  __syncthreads();
  size_t gidx = (size_t)(b * 4096 + c * TC) * 2048 + di;
  for (int t = 0; t < TC; ++t, gidx += 2048) {
    float xv = bf2f(xp[gidx]), dv = bf2f(dt[gidx]), zv = bf2f(zs[gidx]);
    float dvx = dv * xv;
    float y = 0.f;
#pragma unroll
    for (int q = 0; q < 4; ++q) {
      f32x4 bv = ((const f32x4*)(Bs + t * 16))[q];
      f32x4 cv = ((const f32x4*)(Cs + t * 16))[q];
#pragma unroll
      for (int j = 0; j < 4; ++j) {
        int s = q * 4 + j;
        float abar = fmaf(A[s], dv, 1.f);
        h[s] = fmaf(abar, h[s], bv[j] * dvx);
        y = fmaf(cv[j], h[s], y);
      }
    }
    float yo = fmaf(Dg, xv, y) * zv;
    Y[gidx] = f2bf(yo);
  }
}

// ---------------- launch ----------------
extern "C" void kernel_launch(void* const* d_in, const int* in_sizes, int n_in,
                              void* d_out, int out_size, void* d_ws, size_t ws_size,
                              hipStream_t stream) {
  (void)in_sizes; (void)n_in; (void)out_size; (void)ws_size;
  const float* x       = (const float*)d_in[0];  // [2,4096,1024]
  const float* W_in    = (const float*)d_in[1];  // [1024,4096]
  const float* W_xproj = (const float*)d_in[2];  // [2048,96]
  const float* W_dt    = (const float*)d_in[3];  // [64,2048]
  const float* b_dt    = (const float*)d_in[4];  // [2048]
  const float* A_log   = (const float*)d_in[5];  // [2048,16]
  const float* Dv      = (const float*)d_in[6];  // [2048]
  const float* W_out   = (const float*)d_in[7];  // [2048,1024]
  float* out = (float*)d_out;                    // [2,4096,1024] f32

  constexpr size_t MB = 1ull << 20;
  char* ws = (char*)d_ws;
  constexpr size_t O_XP    = 0;                 // xp bf16      [8192][2048] 32MB
  constexpr size_t O_ZS    = 32 * MB;           // silu(z) bf16 [8192][2048] 32MB
  constexpr size_t O_DELTA = 64 * MB;           // delta bf16   [8192][2048] 32MB
  constexpr size_t O_BC    = 96 * MB;           // B f32        [8192][16]  512KB
  constexpr size_t O_CC    = O_BC + 512 * 1024; // C f32        [8192][16]  512KB
  constexpr size_t O_WOUTT = 97 * MB;           // W_out^T bf16 [1024][2048]  4MB
  constexpr size_t O_Y     = 101 * MB;          // Y bf16       [8192][2048] 32MB
  constexpr size_t O_XB    = 133 * MB;          // x bf16       [8192][1024] 16MB
  constexpr size_t O_WINT  = 149 * MB;          // W_in^T bf16  [4096][1024]  8MB
  constexpr size_t O_WXT   = 157 * MB;          // W_xproj^T    [96][2048]  384KB
  constexpr size_t O_WDTT  = O_WXT + 393216;    // W_dt^T       [2048][64]  256KB
  constexpr size_t O_DLT   = O_WDTT + 262144;   // dlt bf16     [8192][64]    1MB
  constexpr size_t O_P     = 133 * MB;          // P f32 16MB (aliases XB, dead after G1)
  constexpr size_t O_Q     = 149 * MB;          // Q f32 16MB (aliases WINT..DLT)
  constexpr size_t O_HIN   = 165 * MB;          // Hin f32 16MB
  constexpr size_t O_XDP   = O_P;               // split-K partials [4][8192][96] f32

  u16* xb    = (u16*)(ws + O_XB);
  u16* WinT  = (u16*)(ws + O_WINT);
  u16* WxT   = (u16*)(ws + O_WXT);
  u16* WdtT  = (u16*)(ws + O_WDTT);
  u16* WoutT = (u16*)(ws + O_WOUTT);
  u16* xpb   = (u16*)(ws + O_XP);
  u16* zsb   = (u16*)(ws + O_ZS);
  u16* dltb  = (u16*)(ws + O_DLT);
  float* Bcf = (float*)(ws + O_BC);
  float* Ccf = (float*)(ws + O_CC);
  u16* delb  = (u16*)(ws + O_DELTA);
  u16* Yb    = (u16*)(ws + O_Y);
  float* Pf  = (float*)(ws + O_P);
  float* Qf  = (float*)(ws + O_Q);
  float* Hin = (float*)(ws + O_HIN);
  float* xdp = (float*)(ws + O_XDP);

  dim3 tb(32, 8);
  f32_to_bf16_kernel<<<8192 * 1024 / 1024, 256, 0, stream>>>(x, xb, 8192 * 1024);
  transpose_f32_bf16T_kernel<<<dim3(4096 / 32, 1024 / 32), tb, 0, stream>>>(W_in, WinT, 1024, 4096);
  transpose_f32_bf16T_kernel<<<dim3(96 / 32, 2048 / 32), tb, 0, stream>>>(W_xproj, WxT, 2048, 96);
  transpose_f32_bf16T_kernel<<<dim3(2048 / 32, 64 / 32), tb, 0, stream>>>(W_dt, WdtT, 64, 2048);
  transpose_f32_bf16T_kernel<<<dim3(1024 / 32, 2048 / 32), tb, 0, stream>>>(W_out, WoutT, 2048, 1024);

  // GEMM1: xz = x @ W_in.  grid 512; col-major walk (gy=32): B L2-resident
  gemm256<256, 0><<<512, 512, 0, stream>>>(
      xb, WinT, 8192, 4096, 1024, 32, xpb, zsb);
  // GEMM2a: x_dbl = xp @ W_xproj, split-K=4 partials then reduce+split
  gemm_bt<96, 3, 4><<<dim3(1, 8192 / 128, 4), 256, 0, stream>>>(
      xpb, WxT, 8192, 96, 2048, 512, xdp, nullptr);
  reduce_xdbl<<<8192 * 24 / 256, 256, 0, stream>>>(xdp, dltb, Bcf, Ccf);
  // GEMM2b: delta = clip(softplus(dlt @ W_dt + b_dt))
  gemm_bt<128, 4, 2><<<dim3(2048 / 128, 8192 / 128, 1), 256, 0, stream>>>(
      dltb, WdtT, 8192, 2048, 64, 64, delb, b_dt);

  // chunked parallel scan: NC=64 chunks of TC=64 steps
  constexpr int NC = 64, TC = 64;
  scan_pass1<TC><<<dim3(8, NC, 2), 256, 0, stream>>>(
      xpb, delb, Bcf, A_log, Pf, Qf, NC);
  scan_pass2<<<dim3(8, 16, 2), 256, 0, stream>>>(Pf, Qf, Hin, NC);
  scan_pass3<TC><<<dim3(8, NC, 2), 256, 0, stream>>>(
      xpb, delb, zsb, Bcf, Ccf, A_log, Dv, Hin, Yb, NC);

  // GEMM3: out = Y @ W_out.  grid 256; col-major walk (gy=32)
  gemm256<128, 3><<<256, 512, 0, stream>>>(
      Yb, WoutT, 8192, 1024, 2048, 32, out, nullptr);
}

// Round 13
// 363.820 us; speedup vs baseline: 1.2183x; 1.2183x over previous
//
#include <hip/hip_runtime.h>
#include <cstdint>
#include <cstddef>

typedef unsigned short u16;
typedef __attribute__((ext_vector_type(8))) short bf16x8;
typedef __attribute__((ext_vector_type(4))) float f32x4;

__device__ __forceinline__ float bf2f(u16 u) {
  unsigned v = ((unsigned)u) << 16;
  return __builtin_bit_cast(float, v);
}
__device__ __forceinline__ u16 f2bf(float f) {
  unsigned u = __builtin_bit_cast(unsigned, f);
  u = (u + 0x7FFFu + ((u >> 16) & 1u)) >> 16;
  return (u16)u;
}

// async global->LDS, 16B per lane. LDS dest semantics: wave-uniform base + lane*16.
__device__ __forceinline__ void gload16(const void* g, void* l) {
  __builtin_amdgcn_global_load_lds(
      (const __attribute__((address_space(1))) void*)g,
      (__attribute__((address_space(3))) void*)l,
      16, 0, 0);
}

// XOR swizzle for 256B-row tiles (BK=128): 16B-slot bits (6:4) ^= row bits
// (10:8). Involution (bits 10:8 untouched). 16 row-consecutive lanes ->
// 8 distinct slots x 2-way (2-way is free, m136).
__device__ __forceinline__ int swzA(int lb) { return lb ^ (((lb >> 8) & 7) << 4); }

// ---------------- elementwise f32 -> bf16 ----------------
__global__ __launch_bounds__(256) void f32_to_bf16_kernel(
    const float* __restrict__ in, u16* __restrict__ out, int n) {
  int i = (blockIdx.x * 256 + threadIdx.x) * 4;
  if (i < n) {
    float4 v = *(const float4*)(in + i);
    ushort4 o;
    o.x = f2bf(v.x); o.y = f2bf(v.y); o.z = f2bf(v.z); o.w = f2bf(v.w);
    *(ushort4*)(out + i) = o;
  }
}

// ---------------- transpose f32[R][C] -> bf16[C][R] ----------------
__global__ void transpose_f32_bf16T_kernel(
    const float* __restrict__ in, u16* __restrict__ out, int R, int C) {
  __shared__ float tile[32][33];
  const int bx = blockIdx.x * 32;  // C coord
  const int by = blockIdx.y * 32;  // R coord
  const int tx = threadIdx.x, ty = threadIdx.y;  // (32,8)
#pragma unroll
  for (int i = 0; i < 32; i += 8)
    tile[ty + i][tx] = in[(size_t)(by + ty + i) * C + bx + tx];
  __syncthreads();
#pragma unroll
  for (int i = 0; i < 32; i += 8)
    out[(size_t)(bx + ty + i) * R + by + tx] = f2bf(tile[tx][ty + i]);
}

// ===== 256-wide MFMA GEMM, BK=128, two k-halves, sparse-barrier schedule =====
// C[M][N] = A[M][K] * Bt[N][K]^T. BM=256, BK=128, BN in {256,128}. 8 waves.
// r4-r9 invariance: time ~ (iterations/CU) x fixed sync cost, independent of
// MFMA/read count. BK=128 halves iterations AND the barrier pairs exist only
// to order in-place staging vs cooperative reads -> k-half 0 (no staging)
// needs only 2 drain-barriers; k-half 1 carries the 4-barrier r9 skeleton.
// 6 barriers + 3 drains per 128-K vs r9's 16+6.
// Units (8KB each, filled by all 8 waves): A: unit i = rows[32i..32i+32);
// A-lo={0,1,4,5} A-hi={2,3,6,7}. B (row-permuted so lo col-halves are
// contiguous): B-lo = first half units, B-hi = second.
// In-place overwrite (khalf1 only): p2: U1(A-lo),U2(B-lo); p3: U4(B-hi);
// p4: U3(A-hi). Counted drains: khalf0-p1 vmcnt(4) [U4 landed], khalf0-p2
// vmcnt(0) [U3; ~4 phases old], khalf1-p4 vmcnt(8|6) [U1,U2 landed].
// EPI 0: split xz -> xp bf16 / silu(z) bf16, ld 2048.  EPI 3: f32 store, ld N.
template <int BN, int EPI>
__global__ __launch_bounds__(512, 2) void gemm256(
    const u16* __restrict__ Ap, const u16* __restrict__ Btp,
    int M, int N, int K, int gx,
    void* __restrict__ o0, void* __restrict__ o1) {
  constexpr int NFR = BN / 64;       // n-frags per wave (4 or 2)
  constexpr int NFH = NFR / 2;       // n-frags per quadrant
  constexpr int WN = BN / 4;         // wave's N extent
  constexpr int HSH = (BN == 256) ? 5 : 4;  // log2(WN/2)
  constexpr int NBU = BN / 32;       // B units (8 or 4)
  constexpr int AREG = 65536;        // A region: 256 rows x 256B
  __shared__ __align__(1024) char smem[AREG + BN * 256];

  const int tid = threadIdx.x;
  const int wid = tid >> 6, lane = tid & 63;
  const int wr = wid >> 2, wc = wid & 3;
  const int l16 = lane & 15, lk = lane >> 4;

  // bijective XCD swizzle (gridDim.x % 8 == 0) + row-major walk
  const int nwg = gridDim.x, bid = blockIdx.x;
  const int rb = (bid & 7) * (nwg >> 3) + (bid >> 3);
  const int bx = rb % gx, by = rb / gx;
  const int m0 = by * 256, n0 = bx * BN;

  // staging sources (inverse-swizzled per-lane global addr, rule #21)
  unsigned aoff[8];
#pragma unroll
  for (int i = 0; i < 8; ++i) {
    int lb = swzA(i * 8192 + tid * 16);
    aoff[i] = (unsigned)(m0 + (lb >> 8)) * K + ((lb & 255) >> 1);
  }
  unsigned boff_g[NBU];
#pragma unroll
  for (int i = 0; i < NBU; ++i) {
    int lb = swzA(i * 8192 + tid * 16);
    int rl = lb >> 8;
    int half = (rl >= BN / 2) ? 1 : 0;
    int r = rl & (BN / 2 - 1);
    int n = ((r >> HSH) << (HSH + 1)) + (half << HSH) + (r & ((1 << HSH) - 1));
    boff_g[i] = (unsigned)(n0 + n) * K + ((lb & 255) >> 1);
  }

  auto stageA = [&](int kt, int h) {  // h=0: units 0,1,4,5  h=1: 2,3,6,7
    const int u0 = h * 2;
    gload16(Ap + aoff[u0] + kt * 128,     smem + u0 * 8192 + (wid << 10));
    gload16(Ap + aoff[u0 + 1] + kt * 128, smem + (u0 + 1) * 8192 + (wid << 10));
    gload16(Ap + aoff[u0 + 4] + kt * 128, smem + (u0 + 4) * 8192 + (wid << 10));
    gload16(Ap + aoff[u0 + 5] + kt * 128, smem + (u0 + 5) * 8192 + (wid << 10));
  };
  auto stageB = [&](int kt, int h) {
#pragma unroll
    for (int j = 0; j < NBU / 2; ++j) {
      int u = h * (NBU / 2) + j;
      gload16(Btp + boff_g[u] + kt * 128, smem + AREG + u * 8192 + (wid << 10));
    }
  };

  auto offA = [&](int f, int kk) {
    return swzA((wr * 128 + f * 16 + l16) * 256 + kk * 64 + lk * 16);
  };
  auto offB = [&](int nf, int kk) {
    int rl = (nf >= NFH ? BN / 2 : 0) + wc * (WN / 2) + (nf % NFH) * 16 + l16;
    return AREG + swzA(rl * 256 + kk * 64 + lk * 16);
  };

  f32x4 acc[8][NFR];
#pragma unroll
  for (int f = 0; f < 8; ++f)
#pragma unroll
    for (int n = 0; n < NFR; ++n) {
      f32x4 z = {0.f, 0.f, 0.f, 0.f};
      acc[f][n] = z;
    }

  const int NT = K >> 7;  // BK=128 tiles (>= 2 for all our launches)

  // prologue: FIFO order U1(A-lo), U2(B-lo), U4(B-hi), U3(A-hi);
  // drain U1,U2 (leave U4+U3 in flight)
  stageA(0, 0); stageB(0, 0); stageB(0, 1); stageA(0, 1);
  if constexpr (BN == 256) asm volatile("s_waitcnt vmcnt(8)" ::: "memory");
  else                     asm volatile("s_waitcnt vmcnt(6)" ::: "memory");
  __builtin_amdgcn_s_barrier();

  // one k-half: kb = k-subtile base (0 or 2). stg=false: barrier-light
  // compute half. stg=true: staging skeleton (r9 discipline).
  auto khalf = [&](int kt, int kb, bool stg, bool hasnext) {
    bf16x8 af[4][2], bh[2][NFH][2];
    // ---- p1: read A-lo + B-lo (kk=kb..kb+1); MFMA (m-lo x n-lo)
#pragma unroll
    for (int j = 0; j < 4; ++j)
#pragma unroll
      for (int q = 0; q < 2; ++q)
        af[j][q] = *(const bf16x8*)(smem + offA(j, kb + q));
#pragma unroll
    for (int j = 0; j < NFH; ++j)
#pragma unroll
      for (int q = 0; q < 2; ++q)
        bh[0][j][q] = *(const bf16x8*)(smem + offB(j, kb + q));
    asm volatile("s_waitcnt lgkmcnt(0)" ::: "memory");
    __builtin_amdgcn_sched_barrier(0);
    __builtin_amdgcn_s_setprio(1);
#pragma unroll
    for (int j = 0; j < 4; ++j)
#pragma unroll
      for (int n2 = 0; n2 < NFH; ++n2)
#pragma unroll
        for (int q = 0; q < 2; ++q)
          acc[j][n2] = __builtin_amdgcn_mfma_f32_16x16x32_bf16(
              af[j][q], bh[0][n2][q], acc[j][n2], 0, 0, 0);
    __builtin_amdgcn_s_setprio(0);
    if (!stg) {
      // U4 (B-hi) must be landed before p2's reads (cooperative: all waves)
      asm volatile("s_waitcnt vmcnt(4)" ::: "memory");
    }
    __builtin_amdgcn_s_barrier();  // stg: all waves done reading U1,U2

    // ---- p2: [stg: stage U1,U2(t+1)] read B-hi; MFMA (m-lo x n-hi)
    if (stg && hasnext) { stageA(kt + 1, 0); stageB(kt + 1, 0); }
#pragma unroll
    for (int j = 0; j < NFH; ++j)
#pragma unroll
      for (int q = 0; q < 2; ++q)
        bh[1][j][q] = *(const bf16x8*)(smem + offB(NFH + j, kb + q));
    asm volatile("s_waitcnt lgkmcnt(0)" ::: "memory");
    __builtin_amdgcn_sched_barrier(0);
    __builtin_amdgcn_s_setprio(1);
#pragma unroll
    for (int j = 0; j < 4; ++j)
#pragma unroll
      for (int n2 = 0; n2 < NFH; ++n2)
#pragma unroll
        for (int q = 0; q < 2; ++q)
          acc[j][NFH + n2] = __builtin_amdgcn_mfma_f32_16x16x32_bf16(
              af[j][q], bh[1][n2][q], acc[j][NFH + n2], 0, 0, 0);
    __builtin_amdgcn_s_setprio(0);
    if (!stg) {
      // U3 (A-hi) landed before p3's reads (oldest outstanding; ~4 phases old)
      asm volatile("s_waitcnt vmcnt(0)" ::: "memory");
    }
    __builtin_amdgcn_s_barrier();  // stg: all waves done reading U4

    // ---- p3: [stg: stage U4(t+1)] read A-hi; MFMA (m-hi x n-hi)
    if (stg && hasnext) stageB(kt + 1, 1);
#pragma unroll
    for (int j = 0; j < 4; ++j)
#pragma unroll
      for (int q = 0; q < 2; ++q)
        af[j][q] = *(const bf16x8*)(smem + offA(4 + j, kb + q));
    asm volatile("s_waitcnt lgkmcnt(0)" ::: "memory");
    __builtin_amdgcn_sched_barrier(0);
    __builtin_amdgcn_s_setprio(1);
#pragma unroll
    for (int j = 0; j < 4; ++j)
#pragma unroll
      for (int n2 = 0; n2 < NFH; ++n2)
#pragma unroll
        for (int q = 0; q < 2; ++q)
          acc[4 + j][NFH + n2] = __builtin_amdgcn_mfma_f32_16x16x32_bf16(
              af[j][q], bh[1][n2][q], acc[4 + j][NFH + n2], 0, 0, 0);
    __builtin_amdgcn_s_setprio(0);
    if (stg) __builtin_amdgcn_s_barrier();  // all waves done reading U3

    // ---- p4: [stg: stage U3(t+1)] MFMA (m-hi x n-lo), regs only
    if (stg && hasnext) stageA(kt + 1, 1);
    __builtin_amdgcn_s_setprio(1);
#pragma unroll
    for (int j = 0; j < 4; ++j)
#pragma unroll
      for (int n2 = 0; n2 < NFH; ++n2)
#pragma unroll
        for (int q = 0; q < 2; ++q)
          acc[4 + j][n2] = __builtin_amdgcn_mfma_f32_16x16x32_bf16(
              af[j][q], bh[0][n2][q], acc[4 + j][n2], 0, 0, 0);
    __builtin_amdgcn_s_setprio(0);
    if (stg) {
      if (hasnext) {
        // drain U1,U2(t+1); leave U4(t+1)+U3(t+1) flying
        if constexpr (BN == 256) asm volatile("s_waitcnt vmcnt(8)" ::: "memory");
        else                     asm volatile("s_waitcnt vmcnt(6)" ::: "memory");
      }
      __builtin_amdgcn_s_barrier();
    }
  };

  for (int kt = 0; kt < NT; ++kt) {
    khalf(kt, 0, false, false);
    khalf(kt, 2, true, kt + 1 < NT);
  }

#pragma unroll
  for (int f = 0; f < 8; ++f) {
#pragma unroll
    for (int n = 0; n < NFR; ++n) {
#pragma unroll
      for (int rr = 0; rr < 4; ++rr) {
        const int row = m0 + wr * 128 + f * 16 + lk * 4 + rr;
        const int col = n0 + wc * WN + n * 16 + l16;
        float v = acc[f][n][rr];
        if constexpr (EPI == 0) {
          if (col < 2048) {
            ((u16*)o0)[(size_t)row * 2048 + col] = f2bf(v);
          } else {
            float sv = v / (1.f + __expf(-v));  // silu
            ((u16*)o1)[(size_t)row * 2048 + (col - 2048)] = f2bf(sv);
          }
        } else {
          ((float*)o0)[(size_t)row * (size_t)N + col] = v;
        }
      }
    }
  }
}

// ---------------- small MFMA GEMM (128-tile) for skinny stages ----------------
// K range = [blockIdx.z*KS, blockIdx.z*KS + KS).
// EPI 2: v += bias[col]; softplus; clip(1e-3,0.1); bf16 (ld 2048)
// EPI 4: f32 partial store to o0 + blockIdx.z*M*96 (ld 96, split-K)
template <int BN, int NR, int EPI>
__global__ __launch_bounds__(256) void gemm_bt(
    const u16* __restrict__ A, const u16* __restrict__ Bt,
    int M, int N, int K, int KS,
    void* __restrict__ o0, const float* __restrict__ bias) {
  constexpr int BM = 128, BK = 32, MR = 4;
  __shared__ __align__(16) u16 As[BM * BK];
  __shared__ __align__(16) u16 Bs[BN * BK];
  const int tid = threadIdx.x;
  const int wid = tid >> 6, lane = tid & 63;
  const int wr = wid >> 1, wc = wid & 1;
  const int m0 = blockIdx.y * BM, n0 = blockIdx.x * BN;
  const int l16 = lane & 15, lk = lane >> 4;

  f32x4 acc[MR][NR];
#pragma unroll
  for (int m = 0; m < MR; ++m)
#pragma unroll
    for (int n = 0; n < NR; ++n) {
      f32x4 z = {0.f, 0.f, 0.f, 0.f};
      acc[m][n] = z;
    }

  constexpr int CH_A = (BM * BK * 2) / 1024;
  constexpr int CH_B = (BN * BK * 2) / 1024;

  const int kbeg = blockIdx.z * KS, kend = kbeg + KS;
  for (int k0 = kbeg; k0 < kend; k0 += BK) {
    for (int c = wid; c < CH_A; c += 4) {
      int off = c * 1024 + lane * 16;
      int e = off >> 1;
      int m = e >> 5, kk = e & 31;
      gload16(A + (size_t)(m0 + m) * K + (k0 + kk), (char*)As + off);
    }
    for (int c = wid; c < CH_B; c += 4) {
      int off = c * 1024 + lane * 16;
      int e = off >> 1;
      int n = e >> 5, kk = e & 31;
      gload16(Bt + (size_t)(n0 + n) * K + (k0 + kk), (char*)Bs + off);
    }
    __syncthreads();
    bf16x8 af[MR], bfr[NR];
#pragma unroll
    for (int m = 0; m < MR; ++m)
      af[m] = *(const bf16x8*)(As + (wr * 64 + m * 16 + l16) * BK + lk * 8);
#pragma unroll
    for (int n = 0; n < NR; ++n)
      bfr[n] = *(const bf16x8*)(Bs + (wc * (NR * 16) + n * 16 + l16) * BK + lk * 8);
#pragma unroll
    for (int m = 0; m < MR; ++m)
#pragma unroll
      for (int n = 0; n < NR; ++n)
        acc[m][n] = __builtin_amdgcn_mfma_f32_16x16x32_bf16(af[m], bfr[n], acc[m][n], 0, 0, 0);
    __syncthreads();
  }

#pragma unroll
  for (int m = 0; m < MR; ++m) {
#pragma unroll
    for (int n = 0; n < NR; ++n) {
#pragma unroll
      for (int r = 0; r < 4; ++r) {
        const int row = m0 + wr * 64 + m * 16 + (lane >> 4) * 4 + r;
        const int col = n0 + wc * (NR * 16) + n * 16 + (lane & 15);
        float v = acc[m][n][r];
        if constexpr (EPI == 2) {
          v += bias[col];
          float sp = (v > 20.f) ? v : log1pf(__expf(v));
          sp = fminf(fmaxf(sp, 1e-3f), 0.1f);
          ((u16*)o0)[(size_t)row * 2048 + col] = f2bf(sp);
        } else {
          ((float*)o0)[((size_t)blockIdx.z * M + row) * 96 + col] = v;
        }
      }
    }
  }
}

// ---------------- split-K reduce + dlt/B/C split ----------------
__global__ __launch_bounds__(256) void reduce_xdbl(
    const float* __restrict__ part, u16* __restrict__ dlt,
    float* __restrict__ Bc, float* __restrict__ Cc) {
  int idx = blockIdx.x * 256 + threadIdx.x;  // 8192*24 float4-groups
  int row = idx / 24, c4 = idx % 24;
  const float* p = part + (size_t)row * 96 + c4 * 4;
  f32x4 v = *(const f32x4*)p;
#pragma unroll
  for (int z = 1; z < 4; ++z)
    v += *(const f32x4*)(p + (size_t)z * 8192 * 96);
  int col = c4 * 4;
  if (col < 64) {
    ushort4 o;
    o.x = f2bf(v[0]); o.y = f2bf(v[1]); o.z = f2bf(v[2]); o.w = f2bf(v[3]);
    *(ushort4*)(dlt + (size_t)row * 64 + col) = o;
  } else if (col < 80) {
    *(f32x4*)(Bc + (size_t)row * 16 + (col - 64)) = v;
  } else {
    *(f32x4*)(Cc + (size_t)row * 16 + (col - 80)) = v;
  }
}

// ---------------- chunked parallel selective scan ----------------
template <int TC>
__global__ __launch_bounds__(256) void scan_pass1(
    const u16* __restrict__ xp, const u16* __restrict__ dt,
    const float* __restrict__ Bc, const float* __restrict__ A_log,
    float* __restrict__ P, float* __restrict__ Q, int NC) {
  const int di = blockIdx.x * 256 + threadIdx.x;
  const int c = blockIdx.y, b = blockIdx.z;
  __shared__ __align__(16) float Bs[TC * 16];
  {
    const float* src = Bc + (size_t)(b * 4096 + c * TC) * 16;
    for (int i = threadIdx.x; i < TC * 4; i += 256)
      *(float4*)(Bs + i * 4) = *(const float4*)(src + i * 4);
  }
  float A[16], h[16], Pp[16];
#pragma unroll
  for (int s = 0; s < 16; ++s) {
    A[s] = -__expf(A_log[di * 16 + s]);
    h[s] = 0.f;
    Pp[s] = 1.f;
  }
  __syncthreads();
  size_t gidx = (size_t)(b * 4096 + c * TC) * 2048 + di;
  for (int t = 0; t < TC; ++t, gidx += 2048) {
    float xv = bf2f(xp[gidx]), dv = bf2f(dt[gidx]);
    float dvx = dv * xv;
#pragma unroll
    for (int q = 0; q < 4; ++q) {
      f32x4 bv = ((const f32x4*)(Bs + t * 16))[q];
#pragma unroll
      for (int j = 0; j < 4; ++j) {
        int s = q * 4 + j;
        float abar = fmaf(A[s], dv, 1.f);
        h[s] = fmaf(abar, h[s], bv[j] * dvx);
        Pp[s] *= abar;
      }
    }
  }
  const size_t obase = ((size_t)(b * NC + c) * 16) * 2048 + di;
#pragma unroll
  for (int s = 0; s < 16; ++s) {
    P[obase + (size_t)s * 2048] = Pp[s];
    Q[obase + (size_t)s * 2048] = h[s];
  }
}

__global__ __launch_bounds__(256) void scan_pass2(
    const float* __restrict__ P, const float* __restrict__ Q,
    float* __restrict__ Hin, int NC) {
  const int di = blockIdx.x * 256 + threadIdx.x;
  const int s = blockIdx.y, b = blockIdx.z;
  float hin = 0.f;
  const size_t idx0 = ((size_t)(b * NC) * 16 + s) * 2048 + di;
#pragma unroll 8
  for (int c = 0; c < NC; ++c) {
    size_t idx = idx0 + (size_t)c * (16 * 2048);
    Hin[idx] = hin;
    hin = fmaf(P[idx], hin, Q[idx]);
  }
}

template <int TC>
__global__ __launch_bounds__(256) void scan_pass3(
    const u16* __restrict__ xp, const u16* __restrict__ dt,
    const u16* __restrict__ zs, const float* __restrict__ Bc,
    const float* __restrict__ Cc, const float* __restrict__ A_log,
    const float* __restrict__ Dv, const float* __restrict__ Hin,
    u16* __restrict__ Y, int NC) {
  const int di = blockIdx.x * 256 + threadIdx.x;
  const int c = blockIdx.y, b = blockIdx.z;
  __shared__ __align__(16) float Bs[TC * 16], Cs[TC * 16];
  {
    const float* srcB = Bc + (size_t)(b * 4096 + c * TC) * 16;
    const float* srcC = Cc + (size_t)(b * 4096 + c * TC) * 16;
    for (int i = threadIdx.x; i < TC * 4; i += 256) {
      *(float4*)(Bs + i * 4) = *(const float4*)(srcB + i * 4);
      *(float4*)(Cs + i * 4) = *(const float4*)(srcC + i * 4);
    }
  }
  float A[16], h[16];
  const size_t hbase = ((size_t)(b * NC + c) * 16) * 2048 + di;
#pragma unroll
  for (int s = 0; s < 16; ++s) {
    A[s] = -__expf(A_log[di * 16 + s]);
    h[s] = Hin[hbase + (size_t)s * 2048];
  }
  const float Dg = Dv[di];
  __syncthreads();
  size_t gidx = (size_t)(b * 4096 + c * TC) * 2048 + di;
  for (int t = 0; t < TC; ++t, gidx += 2048) {
    float xv = bf2f(xp[gidx]), dv = bf2f(dt[gidx]), zv = bf2f(zs[gidx]);
    float dvx = dv * xv;
    float y = 0.f;
#pragma unroll
    for (int q = 0; q < 4; ++q) {
      f32x4 bv = ((const f32x4*)(Bs + t * 16))[q];
      f32x4 cv = ((const f32x4*)(Cs + t * 16))[q];
#pragma unroll
      for (int j = 0; j < 4; ++j) {
        int s = q * 4 + j;
        float abar = fmaf(A[s], dv, 1.f);
        h[s] = fmaf(abar, h[s], bv[j] * dvx);
        y = fmaf(cv[j], h[s], y);
      }
    }
    float yo = fmaf(Dg, xv, y) * zv;
    Y[gidx] = f2bf(yo);
  }
}

// ---------------- launch ----------------
extern "C" void kernel_launch(void* const* d_in, const int* in_sizes, int n_in,
                              void* d_out, int out_size, void* d_ws, size_t ws_size,
                              hipStream_t stream) {
  (void)in_sizes; (void)n_in; (void)out_size; (void)ws_size;
  const float* x       = (const float*)d_in[0];  // [2,4096,1024]
  const float* W_in    = (const float*)d_in[1];  // [1024,4096]
  const float* W_xproj = (const float*)d_in[2];  // [2048,96]
  const float* W_dt    = (const float*)d_in[3];  // [64,2048]
  const float* b_dt    = (const float*)d_in[4];  // [2048]
  const float* A_log   = (const float*)d_in[5];  // [2048,16]
  const float* Dv      = (const float*)d_in[6];  // [2048]
  const float* W_out   = (const float*)d_in[7];  // [2048,1024]
  float* out = (float*)d_out;                    // [2,4096,1024] f32

  constexpr size_t MB = 1ull << 20;
  char* ws = (char*)d_ws;
  constexpr size_t O_XP    = 0;                 // xp bf16      [8192][2048] 32MB
  constexpr size_t O_ZS    = 32 * MB;           // silu(z) bf16 [8192][2048] 32MB
  constexpr size_t O_DELTA = 64 * MB;           // delta bf16   [8192][2048] 32MB
  constexpr size_t O_BC    = 96 * MB;           // B f32        [8192][16]  512KB
  constexpr size_t O_CC    = O_BC + 512 * 1024; // C f32        [8192][16]  512KB
  constexpr size_t O_WOUTT = 97 * MB;           // W_out^T bf16 [1024][2048]  4MB
  constexpr size_t O_Y     = 101 * MB;          // Y bf16       [8192][2048] 32MB
  constexpr size_t O_XB    = 133 * MB;          // x bf16       [8192][1024] 16MB
  constexpr size_t O_WINT  = 149 * MB;          // W_in^T bf16  [4096][1024]  8MB
  constexpr size_t O_WXT   = 157 * MB;          // W_xproj^T    [96][2048]  384KB
  constexpr size_t O_WDTT  = O_WXT + 393216;    // W_dt^T       [2048][64]  256KB
  constexpr size_t O_DLT   = O_WDTT + 262144;   // dlt bf16     [8192][64]    1MB
  constexpr size_t O_P     = 133 * MB;          // P f32 16MB (aliases XB, dead after G1)
  constexpr size_t O_Q     = 149 * MB;          // Q f32 16MB (aliases WINT..DLT)
  constexpr size_t O_HIN   = 165 * MB;          // Hin f32 16MB
  constexpr size_t O_XDP   = O_P;               // split-K partials [4][8192][96] f32

  u16* xb    = (u16*)(ws + O_XB);
  u16* WinT  = (u16*)(ws + O_WINT);
  u16* WxT   = (u16*)(ws + O_WXT);
  u16* WdtT  = (u16*)(ws + O_WDTT);
  u16* WoutT = (u16*)(ws + O_WOUTT);
  u16* xpb   = (u16*)(ws + O_XP);
  u16* zsb   = (u16*)(ws + O_ZS);
  u16* dltb  = (u16*)(ws + O_DLT);
  float* Bcf = (float*)(ws + O_BC);
  float* Ccf = (float*)(ws + O_CC);
  u16* delb  = (u16*)(ws + O_DELTA);
  u16* Yb    = (u16*)(ws + O_Y);
  float* Pf  = (float*)(ws + O_P);
  float* Qf  = (float*)(ws + O_Q);
  float* Hin = (float*)(ws + O_HIN);
  float* xdp = (float*)(ws + O_XDP);

  dim3 tb(32, 8);
  f32_to_bf16_kernel<<<8192 * 1024 / 1024, 256, 0, stream>>>(x, xb, 8192 * 1024);
  transpose_f32_bf16T_kernel<<<dim3(4096 / 32, 1024 / 32), tb, 0, stream>>>(W_in, WinT, 1024, 4096);
  transpose_f32_bf16T_kernel<<<dim3(96 / 32, 2048 / 32), tb, 0, stream>>>(W_xproj, WxT, 2048, 96);
  transpose_f32_bf16T_kernel<<<dim3(2048 / 32, 64 / 32), tb, 0, stream>>>(W_dt, WdtT, 64, 2048);
  transpose_f32_bf16T_kernel<<<dim3(1024 / 32, 2048 / 32), tb, 0, stream>>>(W_out, WoutT, 2048, 1024);

  // GEMM1: xz = x @ W_in.  grid 512 = 16x32 tiles, BK=128 (NT=8)
  gemm256<256, 0><<<512, 512, 0, stream>>>(
      xb, WinT, 8192, 4096, 1024, 16, xpb, zsb);
  // GEMM2a: x_dbl = xp @ W_xproj, split-K=4 partials then reduce+split
  gemm_bt<96, 3, 4><<<dim3(1, 8192 / 128, 4), 256, 0, stream>>>(
      xpb, WxT, 8192, 96, 2048, 512, xdp, nullptr);
  reduce_xdbl<<<8192 * 24 / 256, 256, 0, stream>>>(xdp, dltb, Bcf, Ccf);
  // GEMM2b: delta = clip(softplus(dlt @ W_dt + b_dt))
  gemm_bt<128, 4, 2><<<dim3(2048 / 128, 8192 / 128, 1), 256, 0, stream>>>(
      dltb, WdtT, 8192, 2048, 64, 64, delb, b_dt);

  // chunked parallel scan: NC=64 chunks of TC=64 steps
  constexpr int NC = 64, TC = 64;
  scan_pass1<TC><<<dim3(8, NC, 2), 256, 0, stream>>>(
      xpb, delb, Bcf, A_log, Pf, Qf, NC);
  scan_pass2<<<dim3(8, 16, 2), 256, 0, stream>>>(Pf, Qf, Hin, NC);
  scan_pass3<TC><<<dim3(8, NC, 2), 256, 0, stream>>>(
      xpb, delb, zsb, Bcf, Ccf, A_log, Dv, Hin, Yb, NC);

  // GEMM3: out = Y @ W_out.  grid 256 = 8x32 tiles, BK=128 (NT=16)
  gemm256<128, 3><<<256, 512, 0, stream>>>(
      Yb, WoutT, 8192, 1024, 2048, 8, out, nullptr);
}

// Round 14
// 316.206 us; speedup vs baseline: 1.4017x; 1.1506x over previous
//
#include <hip/hip_runtime.h>
#include <cstdint>
#include <cstddef>

typedef unsigned short u16;
typedef __attribute__((ext_vector_type(8))) short bf16x8;
typedef __attribute__((ext_vector_type(4))) float f32x4;

__device__ __forceinline__ float bf2f(u16 u) {
  unsigned v = ((unsigned)u) << 16;
  return __builtin_bit_cast(float, v);
}
__device__ __forceinline__ u16 f2bf(float f) {
  unsigned u = __builtin_bit_cast(unsigned, f);
  u = (u + 0x7FFFu + ((u >> 16) & 1u)) >> 16;
  return (u16)u;
}

// async global->LDS, 16B per lane. LDS dest semantics: wave-uniform base + lane*16.
__device__ __forceinline__ void gload16(const void* g, void* l) {
  __builtin_amdgcn_global_load_lds(
      (const __attribute__((address_space(1))) void*)g,
      (__attribute__((address_space(3))) void*)l,
      16, 0, 0);
}

// Guideline-4 XOR swizzle for 128B-row tiles: 16B-slot bits (6:4) ^= row bits
// (9:7). Involution; verified 0 bank conflicts (round 4).
__device__ __forceinline__ int swz(int lb) { return lb ^ (((lb >> 7) & 7) << 4); }

// ---------------- fused prep: x f32->bf16 + 4 weight transposes ----------------
// Block ranges: [0,8192) convert x (1024 elem/block, float4 vectorized);
// [8192,12288) W_in^T; [12288,12480) W_xproj^T; [12480,12608) W_dt^T;
// [12608,14656) W_out^T. Block-uniform branch, no divergence.
__global__ __launch_bounds__(256) void prep_kernel(
    const float* __restrict__ x, u16* __restrict__ xb,
    const float* __restrict__ W_in, u16* __restrict__ WinT,
    const float* __restrict__ W_xproj, u16* __restrict__ WxT,
    const float* __restrict__ W_dt, u16* __restrict__ WdtT,
    const float* __restrict__ W_out, u16* __restrict__ WoutT) {
  __shared__ float tile[32][33];
  int b = blockIdx.x;
  if (b < 8192) {
    int i = (b * 256 + threadIdx.x) * 4;
    float4 v = *(const float4*)(x + i);
    ushort4 o;
    o.x = f2bf(v.x); o.y = f2bf(v.y); o.z = f2bf(v.z); o.w = f2bf(v.w);
    *(ushort4*)(xb + i) = o;
    return;
  }
  const float* src; u16* dst; int R, C, bx, by;
  if (b < 12288)      { b -= 8192;  src = W_in;    dst = WinT;  R = 1024; C = 4096; bx = b % 128; by = b / 128; }
  else if (b < 12480) { b -= 12288; src = W_xproj; dst = WxT;   R = 2048; C = 96;   bx = b % 3;   by = b / 3; }
  else if (b < 12608) { b -= 12480; src = W_dt;    dst = WdtT;  R = 64;   C = 2048; bx = b % 64;  by = b / 64; }
  else                { b -= 12608; src = W_out;   dst = WoutT; R = 2048; C = 1024; bx = b % 32;  by = b / 32; }
  const int tx = threadIdx.x & 31, ty = threadIdx.x >> 5;  // 32x8
  const int X = bx * 32, Y = by * 32;
#pragma unroll
  for (int i = 0; i < 32; i += 8)
    tile[ty + i][tx] = src[(size_t)(Y + ty + i) * C + X + tx];
  __syncthreads();
#pragma unroll
  for (int i = 0; i < 32; i += 8)
    dst[(size_t)(X + ty + i) * R + Y + tx] = f2bf(tile[tx][ty + i]);
}

// === 256-wide MFMA GEMM, single-buffer IN-PLACE staging (r9, best: 322us) ===
// C[M][N] = A[M][K] * Bt[N][K]^T. BM=256, BK=64, BN in {256,128}. 8 waves.
// SINGLE 64/48 KiB LDS buffer; each stage unit overwritten in place one phase
// after its last read. Units: U1=A-lo (0,2), U2=B-lo, U3=A-hi (1,3), U4=B-hi.
// p1: read U1,U2 | p2: read U4, stage U1,U2(t+1) | p3: read U3, stage U4(t+1)
// | p4: stage U3(t+1). Counted FIFO drains, never 0 mid-loop.
// GEMM lane closed after r3-r13: six schedule variants all at ~7000cyc/K-tile
// /CU (invariant to schedule/occupancy/BN/buffering); this is the best.
// EPI 0: split xz -> xp bf16 / silu(z) bf16, ld 2048.  EPI 3: f32 store, ld N.
template <int BN, int EPI>
__global__ __launch_bounds__(512, 2) void gemm256(
    const u16* __restrict__ Ap, const u16* __restrict__ Btp,
    int M, int N, int K, int gx,
    void* __restrict__ o0, void* __restrict__ o1) {
  constexpr int NFR = BN / 64;       // n-frags per wave (4 or 2)
  constexpr int NFH = NFR / 2;       // n-frags per phase-quadrant
  constexpr int B_ISS = BN / 64;     // 8KB B stage units (4 or 2)
  constexpr int BH = B_ISS / 2;      // gloads per B half (2 or 1)
  constexpr int WN = BN / 4;         // wave's N extent
  constexpr int HSH = (BN == 256) ? 5 : 4;  // log2(WN/2)
  constexpr int AREG = 32768;        // A region bytes (256 rows x 128B)
  constexpr int BREG = BN * 128;
  __shared__ __align__(1024) char smem[AREG + BREG];  // SINGLE buffer

  const int tid = threadIdx.x;
  const int wid = tid >> 6, lane = tid & 63;
  const int wr = wid >> 2, wc = wid & 3;
  const int l16 = lane & 15, lk = lane >> 4;

  // bijective XCD swizzle (nwg % 8 == 0) + row-major walk
  const int nwg = gridDim.x, bid = blockIdx.x;
  const int rb = (bid & 7) * (nwg >> 3) + (bid >> 3);
  const int bx = rb % gx, by = rb / gx;
  const int m0 = by * 256, n0 = bx * BN;

  // staging sources: LDS written linearly -> pre-apply inverse swizzle to the
  // per-lane GLOBAL address (rule #21). B rows PERMUTED so lo column-halves
  // are LDS-contiguous: rl = hi*BN/2 + wc*(WN/2) + r.
  const u16* gA[4];
  const u16* gB[B_ISS];
#pragma unroll
  for (int i = 0; i < 4; ++i) {
    int lb = swz(i * 8192 + tid * 16);
    gA[i] = Ap + (size_t)(m0 + (lb >> 7)) * K + ((lb & 127) >> 1);
  }
#pragma unroll
  for (int i = 0; i < B_ISS; ++i) {
    int lb = swz(i * 8192 + tid * 16);
    int rl = lb >> 7;
    int half = (rl >= BN / 2) ? 1 : 0;
    int r = rl & (BN / 2 - 1);
    int n = ((r >> HSH) << (HSH + 1)) + (half << HSH) + (r & ((1 << HSH) - 1));
    gB[i] = Btp + (size_t)(n0 + n) * K + ((lb & 127) >> 1);
  }

  auto stageA = [&](int kt, int h) {
    char* dst = smem + (wid << 10);
    gload16(gA[h] + kt * 64, dst + h * 8192);
    gload16(gA[h + 2] + kt * 64, dst + (h + 2) * 8192);
  };
  auto stageB = [&](int kt, int h) {
    char* dst = smem + AREG + (wid << 10);
#pragma unroll
    for (int j = 0; j < BH; ++j)
      gload16(gB[h * BH + j] + kt * 64, dst + (h * BH + j) * 8192);
  };

  auto offA = [&](int f, int kk) {
    return swz((wr * 128 + f * 16 + l16) * 128 + kk * 64 + lk * 16);
  };
  auto offB = [&](int nf, int kk) {
    int rl = (nf >= NFH ? BN / 2 : 0) + wc * (WN / 2) + (nf % NFH) * 16 + l16;
    return swz(rl * 128 + kk * 64 + lk * 16);
  };

  f32x4 acc[8][NFR];
#pragma unroll
  for (int f = 0; f < 8; ++f)
#pragma unroll
    for (int n = 0; n < NFR; ++n) {
      f32x4 z = {0.f, 0.f, 0.f, 0.f};
      acc[f][n] = z;
    }

  const char* bufA = smem;
  const char* bufB = smem + AREG;
  const int NT = K >> 6;
  // prologue: stage tile0 in steady-state FIFO order U1,U2,U4,U3;
  // drain U1,U2 (leave U4,U3 = BH+2 flying)
  stageA(0, 0); stageB(0, 0); stageB(0, 1); stageA(0, 1);
  if constexpr (BH == 2) asm volatile("s_waitcnt vmcnt(4)" ::: "memory");
  else                   asm volatile("s_waitcnt vmcnt(3)" ::: "memory");
  __builtin_amdgcn_s_barrier();

  for (int kt = 0; kt < NT; ++kt) {
    bf16x8 af[4][2], bh[2][NFH][2];

    // ---- phase 1: read A-lo + B-lo; MFMA (m-lo x n-lo); drain U4(t)
#pragma unroll
    for (int j = 0; j < 4; ++j)
#pragma unroll
      for (int kk = 0; kk < 2; ++kk)
        af[j][kk] = *(const bf16x8*)(bufA + offA(j, kk));
#pragma unroll
    for (int j = 0; j < NFH; ++j)
#pragma unroll
      for (int kk = 0; kk < 2; ++kk)
        bh[0][j][kk] = *(const bf16x8*)(bufB + offB(j, kk));
    __builtin_amdgcn_s_barrier();
    asm volatile("s_waitcnt lgkmcnt(0)" ::: "memory");
    __builtin_amdgcn_sched_barrier(0);
    __builtin_amdgcn_s_setprio(1);
#pragma unroll
    for (int j = 0; j < 4; ++j)
#pragma unroll
      for (int n2 = 0; n2 < NFH; ++n2)
#pragma unroll
        for (int kk = 0; kk < 2; ++kk)
          acc[j][n2] = __builtin_amdgcn_mfma_f32_16x16x32_bf16(
              af[j][kk], bh[0][n2][kk], acc[j][n2], 0, 0, 0);
    __builtin_amdgcn_s_setprio(0);
    asm volatile("s_waitcnt vmcnt(2)" ::: "memory");  // U4(t) landed
    __builtin_amdgcn_s_barrier();

    // ---- phase 2: read B-hi; stage U1,U2(t+1) in place; MFMA (m-lo x n-hi);
    //      drain U3(t)
#pragma unroll
    for (int j = 0; j < NFH; ++j)
#pragma unroll
      for (int kk = 0; kk < 2; ++kk)
        bh[1][j][kk] = *(const bf16x8*)(bufB + offB(NFH + j, kk));
    if (kt + 1 < NT) { stageA(kt + 1, 0); stageB(kt + 1, 0); }
    __builtin_amdgcn_s_barrier();
    asm volatile("s_waitcnt lgkmcnt(0)" ::: "memory");
    __builtin_amdgcn_sched_barrier(0);
    __builtin_amdgcn_s_setprio(1);
#pragma unroll
    for (int j = 0; j < 4; ++j)
#pragma unroll
      for (int n2 = 0; n2 < NFH; ++n2)
#pragma unroll
        for (int kk = 0; kk < 2; ++kk)
          acc[j][NFH + n2] = __builtin_amdgcn_mfma_f32_16x16x32_bf16(
              af[j][kk], bh[1][n2][kk], acc[j][NFH + n2], 0, 0, 0);
    __builtin_amdgcn_s_setprio(0);
    if (kt + 1 < NT) {
      if constexpr (BH == 2) asm volatile("s_waitcnt vmcnt(4)" ::: "memory");
      else                   asm volatile("s_waitcnt vmcnt(3)" ::: "memory");
    } else {
      asm volatile("s_waitcnt vmcnt(0)" ::: "memory");
    }
    __builtin_amdgcn_s_barrier();

    // ---- phase 3: read A-hi; stage U4(t+1) in place; MFMA (m-hi x n-hi)
#pragma unroll
    for (int j = 0; j < 4; ++j)
#pragma unroll
      for (int kk = 0; kk < 2; ++kk)
        af[j][kk] = *(const bf16x8*)(bufA + offA(4 + j, kk));
    if (kt + 1 < NT) stageB(kt + 1, 1);
    __builtin_amdgcn_s_barrier();
    asm volatile("s_waitcnt lgkmcnt(0)" ::: "memory");
    __builtin_amdgcn_sched_barrier(0);
    __builtin_amdgcn_s_setprio(1);
#pragma unroll
    for (int j = 0; j < 4; ++j)
#pragma unroll
      for (int n2 = 0; n2 < NFH; ++n2)
#pragma unroll
        for (int kk = 0; kk < 2; ++kk)
          acc[4 + j][NFH + n2] = __builtin_amdgcn_mfma_f32_16x16x32_bf16(
              af[j][kk], bh[1][n2][kk], acc[4 + j][NFH + n2], 0, 0, 0);
    __builtin_amdgcn_s_setprio(0);
    __builtin_amdgcn_s_barrier();

    // ---- phase 4: no reads; stage U3(t+1) in place; MFMA (m-hi x n-lo);
    //      drain U1,U2(t+1)
    if (kt + 1 < NT) stageA(kt + 1, 1);
    __builtin_amdgcn_s_setprio(1);
#pragma unroll
    for (int j = 0; j < 4; ++j)
#pragma unroll
      for (int n2 = 0; n2 < NFH; ++n2)
#pragma unroll
        for (int kk = 0; kk < 2; ++kk)
          acc[4 + j][n2] = __builtin_amdgcn_mfma_f32_16x16x32_bf16(
              af[j][kk], bh[0][n2][kk], acc[4 + j][n2], 0, 0, 0);
    __builtin_amdgcn_s_setprio(0);
    if (kt + 1 < NT) {
      if constexpr (BH == 2) asm volatile("s_waitcnt vmcnt(4)" ::: "memory");
      else                   asm volatile("s_waitcnt vmcnt(3)" ::: "memory");
    }
    __builtin_amdgcn_s_barrier();
  }

#pragma unroll
  for (int f = 0; f < 8; ++f) {
#pragma unroll
    for (int n = 0; n < NFR; ++n) {
#pragma unroll
      for (int rr = 0; rr < 4; ++rr) {
        const int row = m0 + wr * 128 + f * 16 + lk * 4 + rr;
        const int col = n0 + wc * WN + n * 16 + l16;
        float v = acc[f][n][rr];
        if constexpr (EPI == 0) {
          if (col < 2048) {
            ((u16*)o0)[(size_t)row * 2048 + col] = f2bf(v);
          } else {
            float sv = v / (1.f + __expf(-v));  // silu
            ((u16*)o1)[(size_t)row * 2048 + (col - 2048)] = f2bf(sv);
          }
        } else {
          ((float*)o0)[(size_t)row * (size_t)N + col] = v;
        }
      }
    }
  }
}

// ---------------- small MFMA GEMM (128-tile) for skinny stages ----------------
// K range = [blockIdx.z*KS, blockIdx.z*KS + KS).
// EPI 2: v += bias[col]; softplus; clip(1e-3,0.1); bf16 (ld 2048)
// EPI 4: f32 partial store to o0 + blockIdx.z*M*96 (ld 96, split-K)
template <int BN, int NR, int EPI>
__global__ __launch_bounds__(256) void gemm_bt(
    const u16* __restrict__ A, const u16* __restrict__ Bt,
    int M, int N, int K, int KS,
    void* __restrict__ o0, const float* __restrict__ bias) {
  constexpr int BM = 128, BK = 32, MR = 4;
  __shared__ __align__(16) u16 As[BM * BK];
  __shared__ __align__(16) u16 Bs[BN * BK];
  const int tid = threadIdx.x;
  const int wid = tid >> 6, lane = tid & 63;
  const int wr = wid >> 1, wc = wid & 1;
  const int m0 = blockIdx.y * BM, n0 = blockIdx.x * BN;
  const int l16 = lane & 15, lk = lane >> 4;

  f32x4 acc[MR][NR];
#pragma unroll
  for (int m = 0; m < MR; ++m)
#pragma unroll
    for (int n = 0; n < NR; ++n) {
      f32x4 z = {0.f, 0.f, 0.f, 0.f};
      acc[m][n] = z;
    }

  constexpr int CH_A = (BM * BK * 2) / 1024;
  constexpr int CH_B = (BN * BK * 2) / 1024;

  const int kbeg = blockIdx.z * KS, kend = kbeg + KS;
  for (int k0 = kbeg; k0 < kend; k0 += BK) {
    for (int c = wid; c < CH_A; c += 4) {
      int off = c * 1024 + lane * 16;
      int e = off >> 1;
      int m = e >> 5, kk = e & 31;
      gload16(A + (size_t)(m0 + m) * K + (k0 + kk), (char*)As + off);
    }
    for (int c = wid; c < CH_B; c += 4) {
      int off = c * 1024 + lane * 16;
      int e = off >> 1;
      int n = e >> 5, kk = e & 31;
      gload16(Bt + (size_t)(n0 + n) * K + (k0 + kk), (char*)Bs + off);
    }
    __syncthreads();
    bf16x8 af[MR], bfr[NR];
#pragma unroll
    for (int m = 0; m < MR; ++m)
      af[m] = *(const bf16x8*)(As + (wr * 64 + m * 16 + l16) * BK + lk * 8);
#pragma unroll
    for (int n = 0; n < NR; ++n)
      bfr[n] = *(const bf16x8*)(Bs + (wc * (NR * 16) + n * 16 + l16) * BK + lk * 8);
#pragma unroll
    for (int m = 0; m < MR; ++m)
#pragma unroll
      for (int n = 0; n < NR; ++n)
        acc[m][n] = __builtin_amdgcn_mfma_f32_16x16x32_bf16(af[m], bfr[n], acc[m][n], 0, 0, 0);
    __syncthreads();
  }

#pragma unroll
  for (int m = 0; m < MR; ++m) {
#pragma unroll
    for (int n = 0; n < NR; ++n) {
#pragma unroll
      for (int r = 0; r < 4; ++r) {
        const int row = m0 + wr * 64 + m * 16 + (lane >> 4) * 4 + r;
        const int col = n0 + wc * (NR * 16) + n * 16 + (lane & 15);
        float v = acc[m][n][r];
        if constexpr (EPI == 2) {
          v += bias[col];
          float sp = (v > 20.f) ? v : log1pf(__expf(v));
          sp = fminf(fmaxf(sp, 1e-3f), 0.1f);
          ((u16*)o0)[(size_t)row * 2048 + col] = f2bf(sp);
        } else {
          ((float*)o0)[((size_t)blockIdx.z * M + row) * 96 + col] = v;
        }
      }
    }
  }
}

// ---------------- split-K reduce + dlt/B/C split ----------------
__global__ __launch_bounds__(256) void reduce_xdbl(
    const float* __restrict__ part, u16* __restrict__ dlt,
    float* __restrict__ Bc, float* __restrict__ Cc) {
  int idx = blockIdx.x * 256 + threadIdx.x;  // 8192*24 float4-groups
  int row = idx / 24, c4 = idx % 24;
  const float* p = part + (size_t)row * 96 + c4 * 4;
  f32x4 v = *(const f32x4*)p;
#pragma unroll
  for (int z = 1; z < 4; ++z)
    v += *(const f32x4*)(p + (size_t)z * 8192 * 96);
  int col = c4 * 4;
  if (col < 64) {
    ushort4 o;
    o.x = f2bf(v[0]); o.y = f2bf(v[1]); o.z = f2bf(v[2]); o.w = f2bf(v[3]);
    *(ushort4*)(dlt + (size_t)row * 64 + col) = o;
  } else if (col < 80) {
    *(f32x4*)(Bc + (size_t)row * 16 + (col - 64)) = v;
  } else {
    *(f32x4*)(Cc + (size_t)row * 16 + (col - 80)) = v;
  }
}

// ---------------- chunked parallel selective scan ----------------
template <int TC>
__global__ __launch_bounds__(256) void scan_pass1(
    const u16* __restrict__ xp, const u16* __restrict__ dt,
    const float* __restrict__ Bc, const float* __restrict__ A_log,
    float* __restrict__ P, float* __restrict__ Q, int NC) {
  const int di = blockIdx.x * 256 + threadIdx.x;
  const int c = blockIdx.y, b = blockIdx.z;
  __shared__ __align__(16) float Bs[TC * 16];
  {
    const float* src = Bc + (size_t)(b * 4096 + c * TC) * 16;
    for (int i = threadIdx.x; i < TC * 4; i += 256)
      *(float4*)(Bs + i * 4) = *(const float4*)(src + i * 4);
  }
  float A[16], h[16], Pp[16];
#pragma unroll
  for (int s = 0; s < 16; ++s) {
    A[s] = -__expf(A_log[di * 16 + s]);
    h[s] = 0.f;
    Pp[s] = 1.f;
  }
  __syncthreads();
  size_t gidx = (size_t)(b * 4096 + c * TC) * 2048 + di;
  for (int t = 0; t < TC; ++t, gidx += 2048) {
    float xv = bf2f(xp[gidx]), dv = bf2f(dt[gidx]);
    float dvx = dv * xv;
#pragma unroll
    for (int q = 0; q < 4; ++q) {
      f32x4 bv = ((const f32x4*)(Bs + t * 16))[q];
#pragma unroll
      for (int j = 0; j < 4; ++j) {
        int s = q * 4 + j;
        float abar = fmaf(A[s], dv, 1.f);
        h[s] = fmaf(abar, h[s], bv[j] * dvx);
        Pp[s] *= abar;
      }
    }
  }
  const size_t obase = ((size_t)(b * NC + c) * 16) * 2048 + di;
#pragma unroll
  for (int s = 0; s < 16; ++s) {
    P[obase + (size_t)s * 2048] = Pp[s];
    Q[obase + (size_t)s * 2048] = h[s];
  }
}

__global__ __launch_bounds__(256) void scan_pass2(
    const float* __restrict__ P, const float* __restrict__ Q,
    float* __restrict__ Hin, int NC) {
  const int di = blockIdx.x * 256 + threadIdx.x;
  const int s = blockIdx.y, b = blockIdx.z;
  float hin = 0.f;
  const size_t idx0 = ((size_t)(b * NC) * 16 + s) * 2048 + di;
#pragma unroll 8
  for (int c = 0; c < NC; ++c) {
    size_t idx = idx0 + (size_t)c * (16 * 2048);
    Hin[idx] = hin;
    hin = fmaf(P[idx], hin, Q[idx]);
  }
}

template <int TC>
__global__ __launch_bounds__(256) void scan_pass3(
    const u16* __restrict__ xp, const u16* __restrict__ dt,
    const u16* __restrict__ zs, const float* __restrict__ Bc,
    const float* __restrict__ Cc, const float* __restrict__ A_log,
    const float* __restrict__ Dv, const float* __restrict__ Hin,
    u16* __restrict__ Y, int NC) {
  const int di = blockIdx.x * 256 + threadIdx.x;
  const int c = blockIdx.y, b = blockIdx.z;
  __shared__ __align__(16) float Bs[TC * 16], Cs[TC * 16];
  {
    const float* srcB = Bc + (size_t)(b * 4096 + c * TC) * 16;
    const float* srcC = Cc + (size_t)(b * 4096 + c * TC) * 16;
    for (int i = threadIdx.x; i < TC * 4; i += 256) {
      *(float4*)(Bs + i * 4) = *(const float4*)(srcB + i * 4);
      *(float4*)(Cs + i * 4) = *(const float4*)(srcC + i * 4);
    }
  }
  float A[16], h[16];
  const size_t hbase = ((size_t)(b * NC + c) * 16) * 2048 + di;
#pragma unroll
  for (int s = 0; s < 16; ++s) {
    A[s] = -__expf(A_log[di * 16 + s]);
    h[s] = Hin[hbase + (size_t)s * 2048];
  }
  const float Dg = Dv[di];
  __syncthreads();
  size_t gidx = (size_t)(b * 4096 + c * TC) * 2048 + di;
  for (int t = 0; t < TC; ++t, gidx += 2048) {
    float xv = bf2f(xp[gidx]), dv = bf2f(dt[gidx]), zv = bf2f(zs[gidx]);
    float dvx = dv * xv;
    float y = 0.f;
#pragma unroll
    for (int q = 0; q < 4; ++q) {
      f32x4 bv = ((const f32x4*)(Bs + t * 16))[q];
      f32x4 cv = ((const f32x4*)(Cs + t * 16))[q];
#pragma unroll
      for (int j = 0; j < 4; ++j) {
        int s = q * 4 + j;
        float abar = fmaf(A[s], dv, 1.f);
        h[s] = fmaf(abar, h[s], bv[j] * dvx);
        y = fmaf(cv[j], h[s], y);
      }
    }
    float yo = fmaf(Dg, xv, y) * zv;
    Y[gidx] = f2bf(yo);
  }
}

// ---------------- launch ----------------
extern "C" void kernel_launch(void* const* d_in, const int* in_sizes, int n_in,
                              void* d_out, int out_size, void* d_ws, size_t ws_size,
                              hipStream_t stream) {
  (void)in_sizes; (void)n_in; (void)out_size; (void)ws_size;
  const float* x       = (const float*)d_in[0];  // [2,4096,1024]
  const float* W_in    = (const float*)d_in[1];  // [1024,4096]
  const float* W_xproj = (const float*)d_in[2];  // [2048,96]
  const float* W_dt    = (const float*)d_in[3];  // [64,2048]
  const float* b_dt    = (const float*)d_in[4];  // [2048]
  const float* A_log   = (const float*)d_in[5];  // [2048,16]
  const float* Dv      = (const float*)d_in[6];  // [2048]
  const float* W_out   = (const float*)d_in[7];  // [2048,1024]
  float* out = (float*)d_out;                    // [2,4096,1024] f32

  constexpr size_t MB = 1ull << 20;
  char* ws = (char*)d_ws;
  constexpr size_t O_XP    = 0;                 // xp bf16      [8192][2048] 32MB
  constexpr size_t O_ZS    = 32 * MB;           // silu(z) bf16 [8192][2048] 32MB
  constexpr size_t O_DELTA = 64 * MB;           // delta bf16   [8192][2048] 32MB
  constexpr size_t O_BC    = 96 * MB;           // B f32        [8192][16]  512KB
  constexpr size_t O_CC    = O_BC + 512 * 1024; // C f32        [8192][16]  512KB
  constexpr size_t O_WOUTT = 97 * MB;           // W_out^T bf16 [1024][2048]  4MB
  constexpr size_t O_Y     = 101 * MB;          // Y bf16       [8192][2048] 32MB
  constexpr size_t O_XB    = 133 * MB;          // x bf16       [8192][1024] 16MB
  constexpr size_t O_WINT  = 149 * MB;          // W_in^T bf16  [4096][1024]  8MB
  constexpr size_t O_WXT   = 157 * MB;          // W_xproj^T    [96][2048]  384KB
  constexpr size_t O_WDTT  = O_WXT + 393216;    // W_dt^T       [2048][64]  256KB
  constexpr size_t O_DLT   = O_WDTT + 262144;   // dlt bf16     [8192][64]    1MB
  constexpr size_t O_P     = 133 * MB;          // P f32 16MB (aliases XB, dead after G1)
  constexpr size_t O_Q     = 149 * MB;          // Q f32 16MB (aliases WINT..DLT)
  constexpr size_t O_HIN   = 165 * MB;          // Hin f32 16MB
  constexpr size_t O_XDP   = O_P;               // split-K partials [4][8192][96] f32

  u16* xb    = (u16*)(ws + O_XB);
  u16* WinT  = (u16*)(ws + O_WINT);
  u16* WxT   = (u16*)(ws + O_WXT);
  u16* WdtT  = (u16*)(ws + O_WDTT);
  u16* WoutT = (u16*)(ws + O_WOUTT);
  u16* xpb   = (u16*)(ws + O_XP);
  u16* zsb   = (u16*)(ws + O_ZS);
  u16* dltb  = (u16*)(ws + O_DLT);
  float* Bcf = (float*)(ws + O_BC);
  float* Ccf = (float*)(ws + O_CC);
  u16* delb  = (u16*)(ws + O_DELTA);
  u16* Yb    = (u16*)(ws + O_Y);
  float* Pf  = (float*)(ws + O_P);
  float* Qf  = (float*)(ws + O_Q);
  float* Hin = (float*)(ws + O_HIN);
  float* xdp = (float*)(ws + O_XDP);

  // fused prep: x convert + 4 weight transposes, one launch
  prep_kernel<<<14656, 256, 0, stream>>>(
      x, xb, W_in, WinT, W_xproj, WxT, W_dt, WdtT, W_out, WoutT);

  // GEMM1: xz = x @ W_in.  grid 512 = 16x32 tiles; 64 KiB LDS (r9 structure)
  gemm256<256, 0><<<512, 512, 0, stream>>>(
      xb, WinT, 8192, 4096, 1024, 16, xpb, zsb);
  // GEMM2a: x_dbl = xp @ W_xproj, split-K=4 partials then reduce+split
  gemm_bt<96, 3, 4><<<dim3(1, 8192 / 128, 4), 256, 0, stream>>>(
      xpb, WxT, 8192, 96, 2048, 512, xdp, nullptr);
  reduce_xdbl<<<8192 * 24 / 256, 256, 0, stream>>>(xdp, dltb, Bcf, Ccf);
  // GEMM2b: delta = clip(softplus(dlt @ W_dt + b_dt))
  gemm_bt<128, 4, 2><<<dim3(2048 / 128, 8192 / 128, 1), 256, 0, stream>>>(
      dltb, WdtT, 8192, 2048, 64, 64, delb, b_dt);

  // chunked parallel scan: NC=64 chunks of TC=64 steps
  constexpr int NC = 64, TC = 64;
  scan_pass1<TC><<<dim3(8, NC, 2), 256, 0, stream>>>(
      xpb, delb, Bcf, A_log, Pf, Qf, NC);
  scan_pass2<<<dim3(8, 16, 2), 256, 0, stream>>>(Pf, Qf, Hin, NC);
  scan_pass3<TC><<<dim3(8, NC, 2), 256, 0, stream>>>(
      xpb, delb, zsb, Bcf, Ccf, A_log, Dv, Hin, Yb, NC);

  // GEMM3: out = Y @ W_out.  grid 256 = 8x32 tiles
  gemm256<128, 3><<<256, 512, 0, stream>>>(
      Yb, WoutT, 8192, 1024, 2048, 8, out, nullptr);
}